// Round 1
// baseline (907.234 us; speedup 1.0000x reference)
//
#include <hip/hip_runtime.h>

// Problem dims
// x,x1,x2: (8,512,32,32) fp32; w1:(256,512,1,1); b1:(256); w2:(512,256,3,3); b2:(512)
// gamma,bn_bias:(512); beta:(1). Output: (8,512,32,32) fp32.
// G = 16 images (8 from x1 -> group0, 8 from x2 -> group1), N = 1024 spatial.

// ---------------- ws layout (floats) ----------------
// w2t  : 2304*512           = 1179648   [k][co] transposed weights
// Y1   : 16*256*1024        = 4194304   conv1 out (also reused as S after conv2 consumes it)
// Y2   : 16*512*1024        = 8388608   conv2 out, normalized in place -> F
// stats: 2*512 sums + 2*512 sumsq = 2048
// S    : aliases Y1 (8*512*512 = 2097152 <= 4194304)

__global__ __launch_bounds__(256) void zero_stats(float* __restrict__ stats) {
  int t = blockIdx.x * 256 + threadIdx.x;
  if (t < 2048) stats[t] = 0.f;
}

// w2t[k*512 + co] = w2[co*2304 + k]
__global__ __launch_bounds__(256) void transpose_w2(const float* __restrict__ w2,
                                                    float* __restrict__ w2t) {
  __shared__ float tile[64][65];
  int k0 = blockIdx.x * 64;   // 36 blocks
  int co0 = blockIdx.y * 64;  // 8 blocks
  int t = threadIdx.x;
#pragma unroll
  for (int j = 0; j < 16; j++) {
    int e = t + 256 * j;
    int r = e >> 6, c = e & 63;  // r = co_local, c = k_local (coalesced in k)
    tile[c][r] = w2[(size_t)(co0 + r) * 2304 + k0 + c];
  }
  __syncthreads();
#pragma unroll
  for (int j = 0; j < 16; j++) {
    int e = t + 256 * j;
    int r = e >> 6, c = e & 63;  // r = k_local, c = co_local (coalesced in co)
    w2t[(size_t)(k0 + r) * 512 + co0 + c] = tile[r][c];
  }
}

// Generic fp32 tiled GEMM: C[m,n] = sum_k A[m,k] * B(...)  , block tile 128(M) x 64(N) x 16(K)
// BTRANS=0: B is K x N row-major (ld = N). BTRANS=1: B is N x K row-major (ld = K).
// EPI=0: += bias[m] (conv1). EPI=1: none (scores). EPI=2: *= bias[0] (beta scale).
// B2 != nullptr: batch z<8 reads Bbase, z>=8 reads B2 (conv1 x1/x2 split).
template <int N, int K, int BTRANS, int EPI>
__global__ __launch_bounds__(256) void gemm128x64(
    const float* __restrict__ Abase, long long aStride,
    const float* __restrict__ Bbase, long long bStride,
    const float* __restrict__ B2,
    float* __restrict__ Cbase, long long cStride,
    const float* __restrict__ bias) {
  alignas(16) __shared__ float As[16][132];
  alignas(16) __shared__ float Bs[16][68];
  int t = threadIdx.x;
  int bz = blockIdx.z;
  const float* A = Abase + (size_t)bz * aStride;
  const float* Bp;
  if (B2 != nullptr)
    Bp = (bz < 8) ? (Bbase + (size_t)bz * bStride) : (B2 + (size_t)(bz - 8) * bStride);
  else
    Bp = Bbase + (size_t)bz * bStride;
  float* Cp = Cbase + (size_t)bz * cStride;
  int m0 = blockIdx.y * 128, n0 = blockIdx.x * 64;
  int tx = t & 15, ty = t >> 4;
  float acc[8][4] = {};
  for (int k0 = 0; k0 < K; k0 += 16) {
    // stage A: 128 rows x 16 k  (512 float4, 2/thread), store transposed As[k][m]
#pragma unroll
    for (int j = 0; j < 2; j++) {
      int e = t + 256 * j;
      int k4 = e & 3, m = e >> 2;
      float4 v = *(const float4*)(A + (size_t)(m0 + m) * K + k0 + k4 * 4);
      As[k4 * 4 + 0][m] = v.x;
      As[k4 * 4 + 1][m] = v.y;
      As[k4 * 4 + 2][m] = v.z;
      As[k4 * 4 + 3][m] = v.w;
    }
    if (BTRANS == 0) {
      // 16 k-rows x 64 n : 256 float4, 1/thread
      int n4 = t & 15, kk = t >> 4;
      float4 v = *(const float4*)(Bp + (size_t)(k0 + kk) * N + n0 + n4 * 4);
      *(float4*)&Bs[kk][n4 * 4] = v;
    } else {
      // 64 n-rows x 16 k : 256 float4, 1/thread, store transposed Bs[k][n]
      int k4 = t & 3, n = t >> 2;
      float4 v = *(const float4*)(Bp + (size_t)(n0 + n) * K + k0 + k4 * 4);
      Bs[k4 * 4 + 0][n] = v.x;
      Bs[k4 * 4 + 1][n] = v.y;
      Bs[k4 * 4 + 2][n] = v.z;
      Bs[k4 * 4 + 3][n] = v.w;
    }
    __syncthreads();
#pragma unroll
    for (int kk = 0; kk < 16; kk++) {
      float a[8], b[4];
      *(float4*)&a[0] = *(const float4*)&As[kk][ty * 8];
      *(float4*)&a[4] = *(const float4*)&As[kk][ty * 8 + 4];
      *(float4*)&b[0] = *(const float4*)&Bs[kk][tx * 4];
#pragma unroll
      for (int i = 0; i < 8; i++)
#pragma unroll
        for (int j = 0; j < 4; j++) acc[i][j] = fmaf(a[i], b[j], acc[i][j]);
    }
    __syncthreads();
  }
  float scale = (EPI == 2) ? bias[0] : 1.f;
#pragma unroll
  for (int i = 0; i < 8; i++) {
    int m = m0 + ty * 8 + i;
    float add = (EPI == 0) ? bias[m] : 0.f;
    float4 v;
    v.x = acc[i][0] * scale + add;
    v.y = acc[i][1] * scale + add;
    v.z = acc[i][2] * scale + add;
    v.w = acc[i][3] * scale + add;
    *(float4*)(Cp + (size_t)m * N + n0 + tx * 4) = v;
  }
}

// conv 3x3 SAME, 256->512, + bias + LeakyReLU + per-channel sum/sumsq atomics.
// Block: 64 out-channels x 128 px (4 image rows) for one image. Thread: 4 co x 8 px.
__global__ __launch_bounds__(256) void conv3x3_lrelu_stats(
    const float* __restrict__ Y1, const float* __restrict__ w2t,
    const float* __restrict__ b2, float* __restrict__ Y2,
    float* __restrict__ stats) {
  alignas(16) __shared__ float ins[8][6][36];   // 8 ci x 6 rows x (34 used, 36 pad)
  alignas(16) __shared__ float wsm[8][9][64];   // 8 ci x 9 taps x 64 co
  int t = threadIdx.x;
  int g = blockIdx.z, co0 = blockIdx.y * 64, y0 = blockIdx.x * 4;
  int tx = t & 15, ty = t >> 4;
  int co_sub = ty * 4;
  int prow = tx >> 2, pcol = (tx & 3) * 8;
  float acc[4][8] = {};
  const float* Yg = Y1 + (size_t)g * 256 * 1024;
  for (int ci0 = 0; ci0 < 256; ci0 += 8) {
    for (int e = t; e < 1728; e += 256) {
      int ci = e / 216, rem = e % 216;
      int r = rem / 36, c = rem % 36;
      int gy = y0 - 1 + r, gx = c - 1;
      float v = 0.f;
      if ((unsigned)gy < 32u && (unsigned)gx < 32u)
        v = Yg[(size_t)(ci0 + ci) * 1024 + gy * 32 + gx];
      ins[ci][r][c] = v;
    }
    for (int e = t; e < 1152; e += 256) {  // 1152 float4 of weights
      int co4 = e & 15, tap = (e >> 4) % 9, ci = e / 144;
      float4 v = *(const float4*)(w2t + (size_t)((ci0 + ci) * 9 + tap) * 512 + co0 + co4 * 4);
      *(float4*)&wsm[ci][tap][co4 * 4] = v;
    }
    __syncthreads();
#pragma unroll
    for (int ci = 0; ci < 8; ci++) {
      float4 w[9];
#pragma unroll
      for (int tap = 0; tap < 9; tap++) w[tap] = *(const float4*)&wsm[ci][tap][co_sub];
#pragma unroll
      for (int dr = 0; dr < 3; dr++) {
        float inw[12];
        *(float4*)&inw[0] = *(const float4*)&ins[ci][prow + dr][pcol];
        *(float4*)&inw[4] = *(const float4*)&ins[ci][prow + dr][pcol + 4];
        *(float4*)&inw[8] = *(const float4*)&ins[ci][prow + dr][pcol + 8];
#pragma unroll
        for (int ds = 0; ds < 3; ds++) {
          float4 wv = w[dr * 3 + ds];
#pragma unroll
          for (int j = 0; j < 8; j++) {
            float iv = inw[ds + j];
            acc[0][j] = fmaf(wv.x, iv, acc[0][j]);
            acc[1][j] = fmaf(wv.y, iv, acc[1][j]);
            acc[2][j] = fmaf(wv.z, iv, acc[2][j]);
            acc[3][j] = fmaf(wv.w, iv, acc[3][j]);
          }
        }
      }
    }
    __syncthreads();
  }
  int orow = y0 + prow;
  float* outp = Y2 + ((size_t)(g * 512 + co0 + co_sub)) * 1024 + orow * 32 + pcol;
  int grp = g >> 3;
#pragma unroll
  for (int i = 0; i < 4; i++) {
    float bb = b2[co0 + co_sub + i];
    float sum = 0.f, sq = 0.f;
    float vals[8];
#pragma unroll
    for (int j = 0; j < 8; j++) {
      float v = acc[i][j] + bb;
      v = v > 0.f ? v : 0.01f * v;
      vals[j] = v;
      sum += v;
      sq = fmaf(v, v, sq);
    }
    *(float4*)(outp + (size_t)i * 1024) = make_float4(vals[0], vals[1], vals[2], vals[3]);
    *(float4*)(outp + (size_t)i * 1024 + 4) = make_float4(vals[4], vals[5], vals[6], vals[7]);
#pragma unroll
    for (int d = 8; d >= 1; d >>= 1) {
      sum += __shfl_down(sum, (unsigned)d, 16);
      sq += __shfl_down(sq, (unsigned)d, 16);
    }
    if (tx == 0) {
      atomicAdd(&stats[grp * 512 + co0 + co_sub + i], sum);
      atomicAdd(&stats[1024 + grp * 512 + co0 + co_sub + i], sq);
    }
  }
}

// In-place BN (training-mode batch stats) + gamma/bias. One float4 per thread.
__global__ __launch_bounds__(256) void bn_normalize(
    float* __restrict__ Y2, const float* __restrict__ stats,
    const float* __restrict__ gamma, const float* __restrict__ bnb) {
  int idx = blockIdx.x * 256 + threadIdx.x;  // 2,097,152 float4 total
  long long e = (long long)idx << 2;
  int c = (int)((e >> 10) & 511);
  int g = (int)(e >> 19);
  int grp = g >> 3;
  float mean = stats[grp * 512 + c] * (1.f / 8192.f);
  float var = stats[1024 + grp * 512 + c] * (1.f / 8192.f) - mean * mean;
  float inv = rsqrtf(var + 1e-5f);
  float sc = gamma[c] * inv;
  float sh = bnb[c] - mean * sc;
  float4 v = *(float4*)(Y2 + e);
  v.x = fmaf(v.x, sc, sh);
  v.y = fmaf(v.y, sc, sh);
  v.z = fmaf(v.z, sc, sh);
  v.w = fmaf(v.w, sc, sh);
  *(float4*)(Y2 + e) = v;
}

// Row softmax over 512, one block per row (8*512 rows), 2 elems/thread.
__global__ __launch_bounds__(256) void softmax_rows(float* __restrict__ S) {
  int row = blockIdx.x;
  float* p = S + (size_t)row * 512;
  int t = threadIdx.x;
  float2 v = *(const float2*)(p + 2 * t);
  float mx = fmaxf(v.x, v.y);
#pragma unroll
  for (int d = 32; d >= 1; d >>= 1) mx = fmaxf(mx, __shfl_xor(mx, d));
  __shared__ float sred[8];
  int wave = t >> 6, lane = t & 63;
  if (lane == 0) sred[wave] = mx;
  __syncthreads();
  float m4 = fmaxf(fmaxf(sred[0], sred[1]), fmaxf(sred[2], sred[3]));
  float ex = expf(v.x - m4), ey = expf(v.y - m4);
  float s = ex + ey;
#pragma unroll
  for (int d = 32; d >= 1; d >>= 1) s += __shfl_xor(s, d);
  if (lane == 0) sred[4 + wave] = s;
  __syncthreads();
  float inv = 1.f / (sred[4] + sred[5] + sred[6] + sred[7]);
  float2 o;
  o.x = ex * inv;
  o.y = ey * inv;
  *(float2*)(p + 2 * t) = o;
}

extern "C" void kernel_launch(void* const* d_in, const int* in_sizes, int n_in,
                              void* d_out, int out_size, void* d_ws, size_t ws_size,
                              hipStream_t stream) {
  const float* x = (const float*)d_in[0];
  const float* x1 = (const float*)d_in[1];
  const float* x2 = (const float*)d_in[2];
  const float* w1 = (const float*)d_in[3];
  const float* b1 = (const float*)d_in[4];
  const float* w2 = (const float*)d_in[5];
  const float* b2 = (const float*)d_in[6];
  const float* gamma = (const float*)d_in[7];
  const float* bnb = (const float*)d_in[8];
  const float* beta = (const float*)d_in[9];
  float* out = (float*)d_out;
  float* ws = (float*)d_ws;

  float* w2t = ws;                          // 1,179,648
  float* Y1 = ws + 1179648;                 // 4,194,304
  float* Y2 = Y1 + 4194304;                 // 8,388,608
  float* stats = Y2 + 8388608;              // 2,048
  float* S = Y1;                            // reuse (Y1 dead after conv3x3)

  zero_stats<<<8, 256, 0, stream>>>(stats);
  transpose_w2<<<dim3(36, 8), 256, 0, stream>>>(w2, w2t);
  // conv1: M=256, N=1024, K=512, 16 images (x1 then x2)
  gemm128x64<1024, 512, 0, 0><<<dim3(16, 2, 16), 256, 0, stream>>>(
      w1, 0LL, x1, 524288LL, x2, Y1, 262144LL, b1);
  // conv2 + bias + LeakyReLU + stats
  conv3x3_lrelu_stats<<<dim3(8, 8, 16), 256, 0, stream>>>(Y1, w2t, b2, Y2, stats);
  // BN normalize in place -> F
  bn_normalize<<<8192, 256, 0, stream>>>(Y2, stats, gamma, bnb);
  // scores: S[b] = F1[b] (512x1024) * F2[b]^T   (M=512,N=512,K=1024)
  gemm128x64<512, 1024, 1, 1><<<dim3(8, 4, 8), 256, 0, stream>>>(
      Y2, 524288LL, Y2 + (size_t)8 * 524288, 524288LL, nullptr, S, 262144LL, nullptr);
  softmax_rows<<<4096, 256, 0, stream>>>(S);
  // out: O[b] = att[b] (512x512) * x[b] (512x1024), scaled by beta
  gemm128x64<1024, 512, 0, 2><<<dim3(16, 4, 8), 256, 0, stream>>>(
      S, 262144LL, x, 524288LL, nullptr, out, 524288LL, beta);
}

// Round 2
// 504.696 us; speedup vs baseline: 1.7976x; 1.7976x over previous
//
#include <hip/hip_runtime.h>

// Dims: x,x1,x2:(8,512,32,32) fp32; w1:(256,512,1,1); b1:(256); w2:(512,256,3,3);
// b2:(512); gamma,bn_bias:(512); beta:(1). Out:(8,512,32,32) fp32.
// G = 16 images (8 from x1 -> group0, 8 from x2 -> group1), N = 1024 spatial.
//
// ws layout (float offsets), 13,764,608 floats = 55.06 MB (same as round 1):
//   Y2    : +0         8,388,608   conv2 out (fp32). conv1's Y1 aliases its first half.
//   Y1t   : +8388608   4,194,304   bf16 hi (2,097,152 fl) + bf16 lo; aliased by S later.
//   w2b   : +12582912  1,179,648   bf16 hi+lo of w2 in [tap][co][ci]
//   stats : +13762560  2,048

typedef __attribute__((ext_vector_type(8))) short bfrag;   // 8 bf16 = 4 VGPR
typedef __attribute__((ext_vector_type(4))) float facc;    // 4 fp32 acc

__device__ __forceinline__ unsigned short bf16_rn(float v) {
  unsigned u = __float_as_uint(v);
  return (unsigned short)((u + 0x7fffu + ((u >> 16) & 1u)) >> 16);
}

__global__ __launch_bounds__(256) void zero_stats(float* __restrict__ stats) {
  int t = blockIdx.x * 256 + threadIdx.x;
  if (t < 2048) stats[t] = 0.f;
}

// w2 [co512][ci256][tap9] fp32 -> w2bhi/lo [tap][co][ci] bf16 (hi/lo split)
__global__ __launch_bounds__(256) void prep_w2(const float* __restrict__ w2,
                                               unsigned short* __restrict__ hi,
                                               unsigned short* __restrict__ lo) {
  int co = blockIdx.x;       // 512
  int ci = threadIdx.x;      // 256
  const float* src = w2 + ((size_t)co * 256 + ci) * 9;
#pragma unroll
  for (int tap = 0; tap < 9; tap++) {
    float v = src[tap];
    unsigned short h = bf16_rn(v);
    float fh = __uint_as_float((unsigned)h << 16);
    unsigned short l = bf16_rn(v - fh);
    size_t idx = ((size_t)tap * 512 + co) * 256 + ci;
    hi[idx] = h;
    lo[idx] = l;
  }
}

// Y1 fp32 [g][ci256][p1024] -> Y1thi/lo [g][p][ci] bf16 hi/lo
__global__ __launch_bounds__(256) void transpose_split(
    const float* __restrict__ Y1, unsigned short* __restrict__ hi,
    unsigned short* __restrict__ lo) {
  __shared__ float tile[32][33];
  int g = blockIdx.z, ci0 = blockIdx.y * 32, p0 = blockIdx.x * 32;
  int t = threadIdx.x;
  {
    int ci_l = t >> 5, p_l = t & 31;
#pragma unroll
    for (int j = 0; j < 4; j++)
      tile[ci_l + 8 * j][p_l] =
          Y1[((size_t)(g * 256 + ci0 + ci_l + 8 * j)) * 1024 + p0 + p_l];
  }
  __syncthreads();
  {
    int p_l = t >> 3, cg = (t & 7) * 4;
    unsigned short hh[4], ll[4];
#pragma unroll
    for (int j = 0; j < 4; j++) {
      float v = tile[cg + j][p_l];
      unsigned short h = bf16_rn(v);
      float fh = __uint_as_float((unsigned)h << 16);
      hh[j] = h;
      ll[j] = bf16_rn(v - fh);
    }
    size_t idx = ((size_t)(g * 1024 + p0 + p_l)) * 256 + ci0 + cg;
    *(ushort4*)(hi + idx) = make_ushort4(hh[0], hh[1], hh[2], hh[3]);
    *(ushort4*)(lo + idx) = make_ushort4(ll[0], ll[1], ll[2], ll[3]);
  }
}

// Generic fp32 tiled GEMM: C[m,n] = sum_k A[m,k]*B, block tile 128M x 64N x 16K.
// BTRANS=0: B is KxN (ld=N). BTRANS=1: B is NxK (ld=K).
// EPI=0: += bias[m]. EPI=1: none. EPI=2: *= bias[0].
template <int N, int K, int BTRANS, int EPI>
__global__ __launch_bounds__(256) void gemm128x64(
    const float* __restrict__ Abase, long long aStride,
    const float* __restrict__ Bbase, long long bStride,
    const float* __restrict__ B2,
    float* __restrict__ Cbase, long long cStride,
    const float* __restrict__ bias) {
  alignas(16) __shared__ float As[16][132];
  alignas(16) __shared__ float Bs[16][68];
  int t = threadIdx.x;
  int bz = blockIdx.z;
  const float* A = Abase + (size_t)bz * aStride;
  const float* Bp;
  if (B2 != nullptr)
    Bp = (bz < 8) ? (Bbase + (size_t)bz * bStride) : (B2 + (size_t)(bz - 8) * bStride);
  else
    Bp = Bbase + (size_t)bz * bStride;
  float* Cp = Cbase + (size_t)bz * cStride;
  int m0 = blockIdx.y * 128, n0 = blockIdx.x * 64;
  int tx = t & 15, ty = t >> 4;
  float acc[8][4] = {};
  for (int k0 = 0; k0 < K; k0 += 16) {
#pragma unroll
    for (int j = 0; j < 2; j++) {
      int e = t + 256 * j;
      int k4 = e & 3, m = e >> 2;
      float4 v = *(const float4*)(A + (size_t)(m0 + m) * K + k0 + k4 * 4);
      As[k4 * 4 + 0][m] = v.x;
      As[k4 * 4 + 1][m] = v.y;
      As[k4 * 4 + 2][m] = v.z;
      As[k4 * 4 + 3][m] = v.w;
    }
    if (BTRANS == 0) {
      int n4 = t & 15, kk = t >> 4;
      float4 v = *(const float4*)(Bp + (size_t)(k0 + kk) * N + n0 + n4 * 4);
      *(float4*)&Bs[kk][n4 * 4] = v;
    } else {
      int k4 = t & 3, n = t >> 2;
      float4 v = *(const float4*)(Bp + (size_t)(n0 + n) * K + k0 + k4 * 4);
      Bs[k4 * 4 + 0][n] = v.x;
      Bs[k4 * 4 + 1][n] = v.y;
      Bs[k4 * 4 + 2][n] = v.z;
      Bs[k4 * 4 + 3][n] = v.w;
    }
    __syncthreads();
#pragma unroll
    for (int kk = 0; kk < 16; kk++) {
      float a[8], b[4];
      *(float4*)&a[0] = *(const float4*)&As[kk][ty * 8];
      *(float4*)&a[4] = *(const float4*)&As[kk][ty * 8 + 4];
      *(float4*)&b[0] = *(const float4*)&Bs[kk][tx * 4];
#pragma unroll
      for (int i = 0; i < 8; i++)
#pragma unroll
        for (int j = 0; j < 4; j++) acc[i][j] = fmaf(a[i], b[j], acc[i][j]);
    }
    __syncthreads();
  }
  float scale = (EPI == 2) ? bias[0] : 1.f;
#pragma unroll
  for (int i = 0; i < 8; i++) {
    int m = m0 + ty * 8 + i;
    float add = (EPI == 0) ? bias[m] : 0.f;
    float4 v;
    v.x = acc[i][0] * scale + add;
    v.y = acc[i][1] * scale + add;
    v.z = acc[i][2] * scale + add;
    v.w = acc[i][3] * scale + add;
    *(float4*)(Cp + (size_t)m * N + n0 + tx * 4) = v;
  }
}

// conv2 3x3 SAME 256->512 as split-bf16 MFMA implicit GEMM.
// Block: 128 co x 128 px (4 image rows), 4 waves of 64co x 64px (4x4 MFMA tiles).
// K-order: tap-major (9 taps x 256 ci), ci chunked by 32. 3 passes: hh + hl + lh.
// Input LDS: [6 rows][34 x][8 chunks of 16B], chunk c at pos (c ^ (x&7)) (XOR swizzle).
// Weight LDS: 3 tap slots x [128 co][8 chunks], chunk c at pos (c ^ (co&7)).
__global__ __launch_bounds__(256, 2) void conv3x3_mfma(
    const unsigned short* __restrict__ Y1thi, const unsigned short* __restrict__ Y1tlo,
    const unsigned short* __restrict__ w2bhi, const unsigned short* __restrict__ w2blo,
    const float* __restrict__ b2, float* __restrict__ Y2,
    float* __restrict__ stats) {
  __shared__ __attribute__((aligned(16))) unsigned char smem[75264];
  const int WOFF = 26112;  // input 204*128 bytes, then 3*128*128 weight bytes
  int t = threadIdx.x;
  int g = blockIdx.z;
  int co_base = blockIdx.y * 128;
  int y0 = blockIdx.x * 4;
  int w = t >> 6, lane = t & 63;
  int lm = lane & 15, q = lane >> 4;
  int co_half = (w & 1) * 64, px_half = (w >> 1) * 64;
  int px_l[4], row_l[4], x_l[4];
#pragma unroll
  for (int i = 0; i < 4; i++) {
    px_l[i] = px_half + i * 16 + lm;
    row_l[i] = px_l[i] >> 5;
    x_l[i] = px_l[i] & 31;
  }
  facc acc[4][4] = {};  // [cotile][pxtile]
  for (int chunk = 0; chunk < 8; chunk++) {
    int ci0 = chunk * 32;
    for (int dy = 0; dy < 3; dy++) {
      __syncthreads();
      if (dy == 0) {
        // stage input chunk: 204 entries x 8 chunks of 16B (hi c=0..3, lo c=4..7)
        for (int u = t; u < 1632; u += 256) {
          int e = u >> 3, c = u & 7;
          int srow = e / 34, xh = e - srow * 34;
          int gy = y0 - 1 + srow, gx = xh - 1;
          uint4 v = make_uint4(0u, 0u, 0u, 0u);
          if ((unsigned)gy < 32u && (unsigned)gx < 32u) {
            const unsigned short* src = (c < 4) ? Y1thi : Y1tlo;
            v = *(const uint4*)(src +
                ((size_t)((g * 32 + gy) * 32 + gx) * 256 + ci0 + (c & 3) * 8));
          }
          *(uint4*)(smem + e * 128 + ((c ^ (xh & 7)) * 16)) = v;
        }
      }
      // stage weights for taps (dy,0..2): 3 slots x 128 co x 8 chunks
      for (int u = t; u < 3072; u += 256) {
        int e = u >> 3, c = u & 7;
        int slot = e >> 7, co = e & 127;
        const unsigned short* src = (c < 4) ? w2bhi : w2blo;
        uint4 v = *(const uint4*)(src +
            ((size_t)((dy * 3 + slot) * 512 + co_base + co) * 256 + ci0 + (c & 3) * 8));
        *(uint4*)(smem + WOFF + e * 128 + ((c ^ (co & 7)) * 16)) = v;
      }
      __syncthreads();
#pragma unroll
      for (int dx = 0; dx < 3; dx++) {
        bfrag ah[4], al[4], bh[4], bl[4];
#pragma unroll
        for (int j = 0; j < 4; j++) {
          int cr = co_half + j * 16 + lm;
          const unsigned char* p = smem + WOFF + dx * 16384 + cr * 128;
          int ph = (q ^ (lm & 7)) * 16;
          ah[j] = *(const bfrag*)(p + ph);
          al[j] = *(const bfrag*)(p + (ph ^ 64));
        }
#pragma unroll
        for (int i = 0; i < 4; i++) {
          int xh = x_l[i] + dx;
          int entry = (row_l[i] + dy) * 34 + xh;
          const unsigned char* p = smem + entry * 128;
          int ph = (q ^ (xh & 7)) * 16;
          bh[i] = *(const bfrag*)(p + ph);
          bl[i] = *(const bfrag*)(p + (ph ^ 64));
        }
#pragma unroll
        for (int j = 0; j < 4; j++)
#pragma unroll
          for (int i = 0; i < 4; i++) {
            acc[j][i] = __builtin_amdgcn_mfma_f32_16x16x32_bf16(ah[j], bh[i], acc[j][i], 0, 0, 0);
            acc[j][i] = __builtin_amdgcn_mfma_f32_16x16x32_bf16(ah[j], bl[i], acc[j][i], 0, 0, 0);
            acc[j][i] = __builtin_amdgcn_mfma_f32_16x16x32_bf16(al[j], bh[i], acc[j][i], 0, 0, 0);
          }
      }
    }
  }
  // epilogue: + bias, LeakyReLU, store, per-channel stats
  int grp = g >> 3;
#pragma unroll
  for (int j = 0; j < 4; j++) {
    float sum[4], sq[4];
#pragma unroll
    for (int r = 0; r < 4; r++) {
      int co = co_base + co_half + j * 16 + q * 4 + r;
      float bb = b2[co];
      float s = 0.f, s2 = 0.f;
#pragma unroll
      for (int i = 0; i < 4; i++) {
        float v = acc[j][i][r] + bb;
        v = v > 0.f ? v : 0.01f * v;
        int px = blockIdx.x * 128 + px_l[i];
        Y2[((size_t)(g * 512 + co)) * 1024 + px] = v;
        s += v;
        s2 = fmaf(v, v, s2);
      }
      sum[r] = s;
      sq[r] = s2;
    }
#pragma unroll
    for (int r = 0; r < 4; r++) {
      float s = sum[r], s2 = sq[r];
#pragma unroll
      for (int d = 1; d <= 8; d <<= 1) {
        s += __shfl_xor(s, d);
        s2 += __shfl_xor(s2, d);
      }
      if (lm == 0) {
        int co = co_base + co_half + j * 16 + q * 4 + r;
        atomicAdd(&stats[grp * 512 + co], s);
        atomicAdd(&stats[1024 + grp * 512 + co], s2);
      }
    }
  }
}

// In-place BN (training-mode batch stats) + gamma/bias. One float4 per thread.
__global__ __launch_bounds__(256) void bn_normalize(
    float* __restrict__ Y2, const float* __restrict__ stats,
    const float* __restrict__ gamma, const float* __restrict__ bnb) {
  int idx = blockIdx.x * 256 + threadIdx.x;
  long long e = (long long)idx << 2;
  int c = (int)((e >> 10) & 511);
  int g = (int)(e >> 19);
  int grp = g >> 3;
  float mean = stats[grp * 512 + c] * (1.f / 8192.f);
  float var = stats[1024 + grp * 512 + c] * (1.f / 8192.f) - mean * mean;
  float inv = rsqrtf(var + 1e-5f);
  float sc = gamma[c] * inv;
  float sh = bnb[c] - mean * sc;
  float4 v = *(float4*)(Y2 + e);
  v.x = fmaf(v.x, sc, sh);
  v.y = fmaf(v.y, sc, sh);
  v.z = fmaf(v.z, sc, sh);
  v.w = fmaf(v.w, sc, sh);
  *(float4*)(Y2 + e) = v;
}

// Row softmax over 512, one block per row (8*512 rows), 2 elems/thread.
__global__ __launch_bounds__(256) void softmax_rows(float* __restrict__ S) {
  int row = blockIdx.x;
  float* p = S + (size_t)row * 512;
  int t = threadIdx.x;
  float2 v = *(const float2*)(p + 2 * t);
  float mx = fmaxf(v.x, v.y);
#pragma unroll
  for (int d = 32; d >= 1; d >>= 1) mx = fmaxf(mx, __shfl_xor(mx, d));
  __shared__ float sred[8];
  int wave = t >> 6, lane = t & 63;
  if (lane == 0) sred[wave] = mx;
  __syncthreads();
  float m4 = fmaxf(fmaxf(sred[0], sred[1]), fmaxf(sred[2], sred[3]));
  float ex = expf(v.x - m4), ey = expf(v.y - m4);
  float s = ex + ey;
#pragma unroll
  for (int d = 32; d >= 1; d >>= 1) s += __shfl_xor(s, d);
  if (lane == 0) sred[4 + wave] = s;
  __syncthreads();
  float inv = 1.f / (sred[4] + sred[5] + sred[6] + sred[7]);
  float2 o;
  o.x = ex * inv;
  o.y = ey * inv;
  *(float2*)(p + 2 * t) = o;
}

extern "C" void kernel_launch(void* const* d_in, const int* in_sizes, int n_in,
                              void* d_out, int out_size, void* d_ws, size_t ws_size,
                              hipStream_t stream) {
  const float* x = (const float*)d_in[0];
  const float* x1 = (const float*)d_in[1];
  const float* x2 = (const float*)d_in[2];
  const float* w1 = (const float*)d_in[3];
  const float* b1 = (const float*)d_in[4];
  const float* w2 = (const float*)d_in[5];
  const float* b2 = (const float*)d_in[6];
  const float* gamma = (const float*)d_in[7];
  const float* bnb = (const float*)d_in[8];
  const float* beta = (const float*)d_in[9];
  float* out = (float*)d_out;
  float* ws = (float*)d_ws;

  float* Y2 = ws;                                   // 8,388,608 fl
  float* Y1 = ws;                                   // aliases Y2 first half (dead before conv2 writes)
  unsigned short* Y1thi = (unsigned short*)(ws + 8388608);   // 4,194,304 us
  unsigned short* Y1tlo = Y1thi + 4194304;                   // 4,194,304 us
  float* S = ws + 8388608;                          // aliases Y1t (dead after conv2)
  unsigned short* w2bhi = (unsigned short*)(ws + 12582912);  // 1,179,648 us
  unsigned short* w2blo = w2bhi + 1179648;
  float* stats = ws + 13762560;                     // 2,048

  zero_stats<<<8, 256, 0, stream>>>(stats);
  prep_w2<<<512, 256, 0, stream>>>(w2, w2bhi, w2blo);
  // conv1: M=256 co, N=1024 px, K=512, 16 images (x1 then x2) -> Y1 fp32
  gemm128x64<1024, 512, 0, 0><<<dim3(16, 2, 16), 256, 0, stream>>>(
      w1, 0LL, x1, 524288LL, x2, Y1, 262144LL, b1);
  // Y1 -> Y1t bf16 hi/lo, [g][px][ci]
  transpose_split<<<dim3(32, 8, 16), 256, 0, stream>>>(Y1, Y1thi, Y1tlo);
  // conv2 + bias + LeakyReLU + stats (split-bf16 MFMA)
  conv3x3_mfma<<<dim3(8, 4, 16), 256, 0, stream>>>(Y1thi, Y1tlo, w2bhi, w2blo, b2, Y2, stats);
  // BN normalize in place -> F
  bn_normalize<<<8192, 256, 0, stream>>>(Y2, stats, gamma, bnb);
  // scores: S[b] = F1[b] (512x1024) * F2[b]^T
  gemm128x64<512, 1024, 1, 1><<<dim3(8, 4, 8), 256, 0, stream>>>(
      Y2, 524288LL, Y2 + (size_t)8 * 524288, 524288LL, nullptr, S, 262144LL, nullptr);
  softmax_rows<<<4096, 256, 0, stream>>>(S);
  // out: O[b] = att[b] (512x512) * x[b] (512x1024), scaled by beta
  gemm128x64<1024, 512, 0, 2><<<dim3(16, 4, 8), 256, 0, stream>>>(
      S, 262144LL, x, 524288LL, nullptr, out, 524288LL, beta);
}

// Round 3
// 360.596 us; speedup vs baseline: 2.5159x; 1.3996x over previous
//
#include <hip/hip_runtime.h>

// Dims: x,x1,x2:(8,512,32,32) fp32; w1:(256,512,1,1); b1:(256); w2:(512,256,3,3);
// b2:(512); gamma,bn_bias:(512); beta:(1). Out:(8,512,32,32) fp32.
// G = 16 images (8 from x1 -> group0, 8 from x2 -> group1), N = 1024 spatial.
//
// ws layout (float offsets), total 13,772,800 fl = 55.09 MB:
//  [0        : 8388608 ) RF : x12t hi/lo (steps 2-3)  ->  F=yhat hi/lo (conv2 out)
//                           ->  xt hi/lo (after scores, first half)
//  [8388608  : 12582912) RY : Y1t hi/lo (conv1 out)   ->  S fp32 / att hi-lo in place
//  [12582912 : 13762560) w2b hi/lo  [tap][co][ci]
//  [13762560 : 13764608) stats (sum, sumsq per group x 512)
//  [13764608 : 13772800) rowsum [16][512]

typedef __attribute__((ext_vector_type(8))) short bfrag;   // 8 bf16 = 4 VGPR
typedef __attribute__((ext_vector_type(4))) float facc;    // 4 fp32 acc

__device__ __forceinline__ unsigned short bf16_rn(float v) {
  unsigned u = __float_as_uint(v);
  return (unsigned short)((u + 0x7fffu + ((u >> 16) & 1u)) >> 16);
}

__global__ __launch_bounds__(256) void zero_stats(float* __restrict__ stats) {
  int t = blockIdx.x * 256 + threadIdx.x;
  if (t < 10240) stats[t] = 0.f;
}

// w2 [co512][ci256][tap9] fp32 -> w2bhi/lo [tap][co][ci] bf16 (hi/lo split)
__global__ __launch_bounds__(256) void prep_w2(const float* __restrict__ w2,
                                               unsigned short* __restrict__ hi,
                                               unsigned short* __restrict__ lo) {
  int co = blockIdx.x;
  int ci = threadIdx.x;
  const float* src = w2 + ((size_t)co * 256 + ci) * 9;
#pragma unroll
  for (int tap = 0; tap < 9; tap++) {
    float v = src[tap];
    unsigned short h = bf16_rn(v);
    float fh = __uint_as_float((unsigned)h << 16);
    unsigned short l = bf16_rn(v - fh);
    size_t idx = ((size_t)tap * 512 + co) * 256 + ci;
    hi[idx] = h;
    lo[idx] = l;
  }
}

// fp32 [z][512 ci][1024 px] -> [z][px][512 ci] bf16 hi/lo. z<8: src0, z>=8: src1.
__global__ __launch_bounds__(256) void transpose_split(
    const float* __restrict__ src0, const float* __restrict__ src1,
    unsigned short* __restrict__ hi, unsigned short* __restrict__ lo) {
  __shared__ float tile[32][33];
  int z = blockIdx.z;
  const float* src = (z < 8) ? src0 + (size_t)z * 524288 : src1 + (size_t)(z - 8) * 524288;
  int ci0 = blockIdx.y * 32, p0 = blockIdx.x * 32;
  int t = threadIdx.x;
  {
    int ci_l = t >> 5, p_l = t & 31;
#pragma unroll
    for (int j = 0; j < 4; j++)
      tile[ci_l + 8 * j][p_l] = src[(size_t)(ci0 + ci_l + 8 * j) * 1024 + p0 + p_l];
  }
  __syncthreads();
  {
    int p_l = t >> 3, cg = (t & 7) * 4;
    unsigned short hh[4], ll[4];
#pragma unroll
    for (int j = 0; j < 4; j++) {
      float v = tile[cg + j][p_l];
      hh[j] = bf16_rn(v);
      ll[j] = bf16_rn(v - __uint_as_float((unsigned)hh[j] << 16));
    }
    size_t idx = ((size_t)z * 1024 + p0 + p_l) * 512 + ci0 + cg;
    *(ushort4*)(hi + idx) = make_ushort4(hh[0], hh[1], hh[2], hh[3]);
    *(ushort4*)(lo + idx) = make_ushort4(ll[0], ll[1], ll[2], ll[3]);
  }
}

// Split-bf16 3-pass NT MFMA GEMM: D[m][n] = sum_k A[m][k]*B[n][k].
// Block 128x128, 4 waves 2x2, wave = 4x4 tiles of 16x16x32, K-step 64.
// LDS per operand row: 256 B = 16 chunks of 16 B; chunk c stored at
// pos ((c&7)^(row&7)) | (c&8)  (hi chunks 0-7, lo 8-15; XOR swizzle, 2 lanes/bank).
// AF32=1: A is fp32 (w1), split in-register during staging.
// EPI 0: +bias[m], emit bf16 hi/lo transposed [z][n][m] (conv1 -> Y1t)
// EPI 1: BN-folded scores epilogue -> S fp32 [z][m][n]
// EPI 2: fp32 store out[z][m][n] * p0[0]
template <int KTOT, int EPI, int AF32>
__global__ __launch_bounds__(256, 2) void gemm_nt(
    const void* __restrict__ Ahi_, const unsigned short* __restrict__ Alo,
    int aLD, long long aBS,
    const unsigned short* __restrict__ Bhi, const unsigned short* __restrict__ Blo,
    int bLD, long long bBS,
    void* __restrict__ out0, void* __restrict__ out1,
    const float* __restrict__ p0, const float* __restrict__ p1,
    const float* __restrict__ p2, const float* __restrict__ p3) {
  __shared__ __attribute__((aligned(16))) unsigned char smem[65536];
  int t = threadIdx.x;
  int z = blockIdx.z;
  int m0 = blockIdx.y * 128, n0 = blockIdx.x * 128;
  int w = t >> 6, lane = t & 63;
  int lm = lane & 15, q = lane >> 4;
  int mh = (w & 1) * 64, nh = (w >> 1) * 64;
  facc acc[4][4] = {};  // [mt][nt]
  for (int k0 = 0; k0 < KTOT; k0 += 64) {
    __syncthreads();
    if (AF32) {
      const float* Af = (const float*)Ahi_ + (size_t)z * aBS;
#pragma unroll
      for (int j = 0; j < 8; j++) {
        int idx = t + 256 * j;
        int row = idx >> 4, c4 = idx & 15;
        float4 v = *(const float4*)(Af + (size_t)(m0 + row) * aLD + k0 + c4 * 4);
        unsigned short h0 = bf16_rn(v.x), h1 = bf16_rn(v.y), h2 = bf16_rn(v.z), h3 = bf16_rn(v.w);
        unsigned short l0 = bf16_rn(v.x - __uint_as_float((unsigned)h0 << 16));
        unsigned short l1 = bf16_rn(v.y - __uint_as_float((unsigned)h1 << 16));
        unsigned short l2 = bf16_rn(v.z - __uint_as_float((unsigned)h2 << 16));
        unsigned short l3 = bf16_rn(v.w - __uint_as_float((unsigned)h3 << 16));
        int base = row * 256 + (((c4 >> 1) ^ (row & 7)) * 16) + (c4 & 1) * 8;
        *(ushort4*)(smem + base) = make_ushort4(h0, h1, h2, h3);
        *(ushort4*)(smem + base + 128) = make_ushort4(l0, l1, l2, l3);
      }
    } else {
      const unsigned short* Ah = (const unsigned short*)Ahi_ + (size_t)z * aBS;
      const unsigned short* Al = Alo + (size_t)z * aBS;
#pragma unroll
      for (int j = 0; j < 8; j++) {
        int idx = t + 256 * j;
        int row = idx >> 4, c = idx & 15;
        const unsigned short* src = (c < 8) ? Ah : Al;
        uint4 v = *(const uint4*)(src + (size_t)(m0 + row) * aLD + k0 + (c & 7) * 8);
        *(uint4*)(smem + row * 256 + ((((c & 7) ^ (row & 7)) | (c & 8)) * 16)) = v;
      }
    }
#pragma unroll
    for (int j = 0; j < 8; j++) {
      int idx = t + 256 * j;
      int row = idx >> 4, c = idx & 15;
      const unsigned short* src = (c < 8) ? Bhi : Blo;
      uint4 v = *(const uint4*)(src + (size_t)z * bBS + (size_t)(n0 + row) * bLD + k0 + (c & 7) * 8);
      *(uint4*)(smem + 32768 + row * 256 + ((((c & 7) ^ (row & 7)) | (c & 8)) * 16)) = v;
    }
    __syncthreads();
#pragma unroll
    for (int ks = 0; ks < 2; ks++) {
      bfrag ah[4], al[4], bh[4], bl[4];
#pragma unroll
      for (int mt = 0; mt < 4; mt++) {
        int m = mh + mt * 16 + lm;
        int phys = ((ks * 4 + q) ^ (m & 7)) * 16;
        const unsigned char* p = smem + m * 256;
        ah[mt] = *(const bfrag*)(p + phys);
        al[mt] = *(const bfrag*)(p + phys + 128);
      }
#pragma unroll
      for (int nt = 0; nt < 4; nt++) {
        int n = nh + nt * 16 + lm;
        int phys = ((ks * 4 + q) ^ (n & 7)) * 16;
        const unsigned char* p = smem + 32768 + n * 256;
        bh[nt] = *(const bfrag*)(p + phys);
        bl[nt] = *(const bfrag*)(p + phys + 128);
      }
#pragma unroll
      for (int mt = 0; mt < 4; mt++)
#pragma unroll
        for (int nt = 0; nt < 4; nt++) {
          acc[mt][nt] = __builtin_amdgcn_mfma_f32_16x16x32_bf16(ah[mt], bh[nt], acc[mt][nt], 0, 0, 0);
          acc[mt][nt] = __builtin_amdgcn_mfma_f32_16x16x32_bf16(ah[mt], bl[nt], acc[mt][nt], 0, 0, 0);
          acc[mt][nt] = __builtin_amdgcn_mfma_f32_16x16x32_bf16(al[mt], bh[nt], acc[mt][nt], 0, 0, 0);
        }
    }
  }
  if (EPI == 0) {
    unsigned short* Oh = (unsigned short*)out0;
    unsigned short* Ol = (unsigned short*)out1;
#pragma unroll
    for (int mt = 0; mt < 4; mt++) {
      int mb = m0 + mh + mt * 16 + q * 4;
#pragma unroll
      for (int nt = 0; nt < 4; nt++) {
        int n = n0 + nh + nt * 16 + lm;
        unsigned short hh[4], ll[4];
#pragma unroll
        for (int r = 0; r < 4; r++) {
          float v = acc[mt][nt][r] + p0[mb + r];
          hh[r] = bf16_rn(v);
          ll[r] = bf16_rn(v - __uint_as_float((unsigned)hh[r] << 16));
        }
        size_t o = ((size_t)(z * 1024 + n)) * 256 + mb;
        *(ushort4*)(Oh + o) = make_ushort4(hh[0], hh[1], hh[2], hh[3]);
        *(ushort4*)(Ol + o) = make_ushort4(ll[0], ll[1], ll[2], ll[3]);
      }
    }
  } else if (EPI == 1) {
    // S = a1*a2*G + a1*t2*r1 + t1*a2*r2 + 1024*t1*t2
    float* S = (float*)out0;
    const float* stats = p0;
    const float* rowsum = p1;
    const float* gamma = p2;
    const float* bnb = p3;
    float a2v[4], t2v[4], r2v[4];
#pragma unroll
    for (int nt = 0; nt < 4; nt++) {
      int d = n0 + nh + nt * 16 + lm;
      float mu = stats[512 + d] * (1.f / 8192.f);
      float var = stats[1536 + d] * (1.f / 8192.f) - mu * mu;
      float a = gamma[d] * rsqrtf(var + 1e-5f);
      a2v[nt] = a;
      t2v[nt] = bnb[d] - mu * a;
      r2v[nt] = rowsum[(8 + z) * 512 + d];
    }
#pragma unroll
    for (int mt = 0; mt < 4; mt++)
#pragma unroll
      for (int r = 0; r < 4; r++) {
        int c = m0 + mh + mt * 16 + q * 4 + r;
        float mu = stats[c] * (1.f / 8192.f);
        float var = stats[1024 + c] * (1.f / 8192.f) - mu * mu;
        float a1 = gamma[c] * rsqrtf(var + 1e-5f);
        float t1 = bnb[c] - mu * a1;
        float r1 = rowsum[z * 512 + c];
#pragma unroll
        for (int nt = 0; nt < 4; nt++) {
          int d = n0 + nh + nt * 16 + lm;
          float sc = a1 * a2v[nt] * acc[mt][nt][r] + a1 * t2v[nt] * r1 +
                     t1 * a2v[nt] * r2v[nt] + 1024.f * t1 * t2v[nt];
          S[((size_t)(z * 512 + c)) * 512 + d] = sc;
        }
      }
  } else {
    float* O = (float*)out0;
    float sc = p0[0];
#pragma unroll
    for (int mt = 0; mt < 4; mt++)
#pragma unroll
      for (int r = 0; r < 4; r++) {
        int c = m0 + mh + mt * 16 + q * 4 + r;
#pragma unroll
        for (int nt = 0; nt < 4; nt++) {
          int n = n0 + nh + nt * 16 + lm;
          O[((size_t)(z * 512 + c)) * 1024 + n] = sc * acc[mt][nt][r];
        }
      }
  }
}

// conv2 3x3 SAME 256->512 split-bf16 MFMA implicit GEMM.
// Epilogue: +bias, LeakyReLU, emit yhat bf16 hi/lo [g][co][px] + stats + rowsums.
__global__ __launch_bounds__(256, 2) void conv3x3_mfma(
    const unsigned short* __restrict__ Y1thi, const unsigned short* __restrict__ Y1tlo,
    const unsigned short* __restrict__ w2bhi, const unsigned short* __restrict__ w2blo,
    const float* __restrict__ b2, unsigned short* __restrict__ Fhi,
    unsigned short* __restrict__ Flo, float* __restrict__ stats,
    float* __restrict__ rowsum) {
  __shared__ __attribute__((aligned(16))) unsigned char smem[75264];
  const int WOFF = 26112;
  int t = threadIdx.x;
  int g = blockIdx.z;
  int co_base = blockIdx.y * 128;
  int y0 = blockIdx.x * 4;
  int w = t >> 6, lane = t & 63;
  int lm = lane & 15, q = lane >> 4;
  int co_half = (w & 1) * 64, px_half = (w >> 1) * 64;
  int px_l[4], row_l[4], x_l[4];
#pragma unroll
  for (int i = 0; i < 4; i++) {
    px_l[i] = px_half + i * 16 + lm;
    row_l[i] = px_l[i] >> 5;
    x_l[i] = px_l[i] & 31;
  }
  facc acc[4][4] = {};
  for (int chunk = 0; chunk < 8; chunk++) {
    int ci0 = chunk * 32;
    for (int dy = 0; dy < 3; dy++) {
      __syncthreads();
      if (dy == 0) {
        for (int u = t; u < 1632; u += 256) {
          int e = u >> 3, c = u & 7;
          int srow = e / 34, xh = e - srow * 34;
          int gy = y0 - 1 + srow, gx = xh - 1;
          uint4 v = make_uint4(0u, 0u, 0u, 0u);
          if ((unsigned)gy < 32u && (unsigned)gx < 32u) {
            const unsigned short* src = (c < 4) ? Y1thi : Y1tlo;
            v = *(const uint4*)(src +
                ((size_t)((g * 32 + gy) * 32 + gx) * 256 + ci0 + (c & 3) * 8));
          }
          *(uint4*)(smem + e * 128 + ((c ^ (xh & 7)) * 16)) = v;
        }
      }
      for (int u = t; u < 3072; u += 256) {
        int e = u >> 3, c = u & 7;
        int slot = e >> 7, co = e & 127;
        const unsigned short* src = (c < 4) ? w2bhi : w2blo;
        uint4 v = *(const uint4*)(src +
            ((size_t)((dy * 3 + slot) * 512 + co_base + co) * 256 + ci0 + (c & 3) * 8));
        *(uint4*)(smem + WOFF + e * 128 + ((c ^ (co & 7)) * 16)) = v;
      }
      __syncthreads();
#pragma unroll
      for (int dx = 0; dx < 3; dx++) {
        bfrag ah[4], al[4], bh[4], bl[4];
#pragma unroll
        for (int j = 0; j < 4; j++) {
          int cr = co_half + j * 16 + lm;
          const unsigned char* p = smem + WOFF + dx * 16384 + cr * 128;
          int ph = (q ^ (lm & 7)) * 16;
          ah[j] = *(const bfrag*)(p + ph);
          al[j] = *(const bfrag*)(p + (ph ^ 64));
        }
#pragma unroll
        for (int i = 0; i < 4; i++) {
          int xh = x_l[i] + dx;
          int entry = (row_l[i] + dy) * 34 + xh;
          const unsigned char* p = smem + entry * 128;
          int ph = (q ^ (xh & 7)) * 16;
          bh[i] = *(const bfrag*)(p + ph);
          bl[i] = *(const bfrag*)(p + (ph ^ 64));
        }
#pragma unroll
        for (int j = 0; j < 4; j++)
#pragma unroll
          for (int i = 0; i < 4; i++) {
            acc[j][i] = __builtin_amdgcn_mfma_f32_16x16x32_bf16(ah[j], bh[i], acc[j][i], 0, 0, 0);
            acc[j][i] = __builtin_amdgcn_mfma_f32_16x16x32_bf16(ah[j], bl[i], acc[j][i], 0, 0, 0);
            acc[j][i] = __builtin_amdgcn_mfma_f32_16x16x32_bf16(al[j], bh[i], acc[j][i], 0, 0, 0);
          }
      }
    }
  }
  int grp = g >> 3;
  int px0 = blockIdx.x * 128;
#pragma unroll
  for (int j = 0; j < 4; j++) {
#pragma unroll
    for (int r = 0; r < 4; r++) {
      int co = co_base + co_half + j * 16 + q * 4 + r;
      float bb = b2[co];
      float s = 0.f, s2 = 0.f;
#pragma unroll
      for (int i = 0; i < 4; i++) {
        float v = acc[j][i][r] + bb;
        v = v > 0.f ? v : 0.01f * v;
        unsigned short h = bf16_rn(v);
        unsigned short l = bf16_rn(v - __uint_as_float((unsigned)h << 16));
        size_t o = ((size_t)(g * 512 + co)) * 1024 + px0 + px_l[i];
        Fhi[o] = h;
        Flo[o] = l;
        s += v;
        s2 = fmaf(v, v, s2);
      }
#pragma unroll
      for (int d = 1; d <= 8; d <<= 1) {
        s += __shfl_xor(s, d);
        s2 += __shfl_xor(s2, d);
      }
      if (lm == 0) {
        atomicAdd(&stats[grp * 512 + co], s);
        atomicAdd(&stats[1024 + grp * 512 + co], s2);
        atomicAdd(&rowsum[g * 512 + co], s);
      }
    }
  }
}

// Row softmax over 512; in place: row's 2 KB becomes att hi [0:512) + lo [512:1024) us.
__global__ __launch_bounds__(256) void softmax_rows(float* __restrict__ S) {
  int row = blockIdx.x;
  float* p = S + (size_t)row * 512;
  int t = threadIdx.x;
  float2 v = *(const float2*)(p + 2 * t);
  float mx = fmaxf(v.x, v.y);
#pragma unroll
  for (int d = 32; d >= 1; d >>= 1) mx = fmaxf(mx, __shfl_xor(mx, d));
  __shared__ float sred[8];
  int wave = t >> 6, lane = t & 63;
  if (lane == 0) sred[wave] = mx;
  __syncthreads();
  float m4 = fmaxf(fmaxf(sred[0], sred[1]), fmaxf(sred[2], sred[3]));
  float ex = expf(v.x - m4), ey = expf(v.y - m4);
  float s = ex + ey;
#pragma unroll
  for (int d = 32; d >= 1; d >>= 1) s += __shfl_xor(s, d);
  if (lane == 0) sred[4 + wave] = s;
  __syncthreads();
  float inv = 1.f / (sred[4] + sred[5] + sred[6] + sred[7]);
  float px_ = ex * inv, py_ = ey * inv;
  unsigned short h0 = bf16_rn(px_), h1 = bf16_rn(py_);
  unsigned short l0 = bf16_rn(px_ - __uint_as_float((unsigned)h0 << 16));
  unsigned short l1 = bf16_rn(py_ - __uint_as_float((unsigned)h1 << 16));
  unsigned short* rh = (unsigned short*)p;
  *(ushort2*)(rh + 2 * t) = make_ushort2(h0, h1);
  *(ushort2*)(rh + 512 + 2 * t) = make_ushort2(l0, l1);
}

extern "C" void kernel_launch(void* const* d_in, const int* in_sizes, int n_in,
                              void* d_out, int out_size, void* d_ws, size_t ws_size,
                              hipStream_t stream) {
  const float* x = (const float*)d_in[0];
  const float* x1 = (const float*)d_in[1];
  const float* x2 = (const float*)d_in[2];
  const float* w1 = (const float*)d_in[3];
  const float* b1 = (const float*)d_in[4];
  const float* w2 = (const float*)d_in[5];
  const float* b2 = (const float*)d_in[6];
  const float* gamma = (const float*)d_in[7];
  const float* bnb = (const float*)d_in[8];
  const float* beta = (const float*)d_in[9];
  float* out = (float*)d_out;
  float* ws = (float*)d_ws;

  // Region RF [0 : 8388608): x12t -> F(yhat) -> xt
  unsigned short* x12thi = (unsigned short*)ws;            // 16x1024x512
  unsigned short* x12tlo = (unsigned short*)(ws + 4194304);
  unsigned short* Fhi = (unsigned short*)ws;               // 16x512x1024
  unsigned short* Flo = (unsigned short*)(ws + 4194304);
  unsigned short* xthi = (unsigned short*)ws;              // 8x1024x512
  unsigned short* xtlo = (unsigned short*)(ws + 2097152);
  // Region RY [8388608 : 12582912): Y1t -> S/att
  unsigned short* Y1thi = (unsigned short*)(ws + 8388608);  // 16x1024x256
  unsigned short* Y1tlo = (unsigned short*)(ws + 10485760);
  float* S = ws + 8388608;                                  // 8x512x512 fp32
  // Persistent
  unsigned short* w2bhi = (unsigned short*)(ws + 12582912);
  unsigned short* w2blo = (unsigned short*)(ws + 13172736);
  float* stats = ws + 13762560;   // 2048
  float* rowsum = ws + 13764608;  // 8192

  zero_stats<<<40, 256, 0, stream>>>(stats);
  prep_w2<<<512, 256, 0, stream>>>(w2, w2bhi, w2blo);
  // x1,x2 -> x12t [g][px][ci] hi/lo
  transpose_split<<<dim3(32, 16, 16), 256, 0, stream>>>(x1, x2, x12thi, x12tlo);
  // conv1: D[co][px] = sum_ci w1*x, +b1, emit Y1t [g][px][co] hi/lo
  gemm_nt<512, 0, 1><<<dim3(8, 2, 16), 256, 0, stream>>>(
      w1, nullptr, 512, 0LL, x12thi, x12tlo, 512, 524288LL,
      Y1thi, Y1tlo, b1, nullptr, nullptr, nullptr);
  // conv2 + bias + LeakyReLU -> yhat split + stats + rowsums
  conv3x3_mfma<<<dim3(8, 4, 16), 256, 0, stream>>>(
      Y1thi, Y1tlo, w2bhi, w2blo, b2, Fhi, Flo, stats, rowsum);
  // scores with BN folded into epilogue -> S fp32
  gemm_nt<1024, 1, 0><<<dim3(4, 4, 8), 256, 0, stream>>>(
      Fhi, Flo, 1024, 524288LL, Fhi + (size_t)8 * 524288, Flo + (size_t)8 * 524288,
      1024, 524288LL, S, nullptr, stats, rowsum, gamma, bnb);
  // x -> xt [b][px][c] hi/lo (F is dead now; overwrites RF front)
  transpose_split<<<dim3(32, 16, 8), 256, 0, stream>>>(x, x, xthi, xtlo);
  // softmax in place -> att hi/lo packed in S rows
  softmax_rows<<<4096, 256, 0, stream>>>(S);
  // out: O[c][px] = beta * sum_d att*xt
  gemm_nt<512, 2, 0><<<dim3(8, 4, 8), 256, 0, stream>>>(
      (unsigned short*)S, (unsigned short*)S + 512, 1024, 524288LL,
      xthi, xtlo, 512, 524288LL, out, nullptr, beta, nullptr, nullptr, nullptr);
}

// Round 4
// 354.555 us; speedup vs baseline: 2.5588x; 1.0170x over previous
//
#include <hip/hip_runtime.h>

// Dims: x,x1,x2:(8,512,32,32) fp32; w1:(256,512,1,1); b1:(256); w2:(512,256,3,3);
// b2:(512); gamma,bn_bias:(512); beta:(1). Out:(8,512,32,32) fp32.
// G = 16 images (8 from x1 -> group0, 8 from x2 -> group1), N = 1024 spatial.
//
// ws layout (float offsets), total 13,772,800 fl = 55.09 MB:
//  [0        : 8388608 ) RF : x12t hi/lo -> F=yhat hi/lo (conv2 out) -> xt hi/lo
//  [8388608  : 12582912) RY : Y1t hi/lo (conv1 out) -> S0 [8388608..10485760)
//                             + S1 partial [10485760..12582912); att in S0 in place
//  [12582912 : 13762560) w2b hi/lo  [tap][co][ci]
//  [13762560 : 13764608) stats (sum, sumsq per group x 512)
//  [13764608 : 13772800) rowsum [16][512]

typedef __attribute__((ext_vector_type(8))) short bfrag;    // 8 bf16 = 4 VGPR
typedef __attribute__((ext_vector_type(4))) float facc;     // 4 fp32 acc
typedef __attribute__((ext_vector_type(16))) float facc16;  // 16 fp32 acc (32x32)

__device__ __forceinline__ unsigned short bf16_rn(float v) {
  unsigned u = __float_as_uint(v);
  return (unsigned short)((u + 0x7fffu + ((u >> 16) & 1u)) >> 16);
}

// w2 [co512][ci256][tap9] fp32 -> w2bhi/lo [tap][co][ci] bf16 (hi/lo split).
// Also zeroes stats+rowsum (10240 floats) from blocks 0..39.
__global__ __launch_bounds__(256) void prep_w2(const float* __restrict__ w2,
                                               unsigned short* __restrict__ hi,
                                               unsigned short* __restrict__ lo,
                                               float* __restrict__ statsz) {
  if (blockIdx.x < 40) statsz[blockIdx.x * 256 + threadIdx.x] = 0.f;
  int co = blockIdx.x;
  int ci = threadIdx.x;
  const float* src = w2 + ((size_t)co * 256 + ci) * 9;
#pragma unroll
  for (int tap = 0; tap < 9; tap++) {
    float v = src[tap];
    unsigned short h = bf16_rn(v);
    float fh = __uint_as_float((unsigned)h << 16);
    unsigned short l = bf16_rn(v - fh);
    size_t idx = ((size_t)tap * 512 + co) * 256 + ci;
    hi[idx] = h;
    lo[idx] = l;
  }
}

// fp32 [z][512 ci][1024 px] -> [z][px][512 ci] bf16 hi/lo. z<8: src0, z>=8: src1.
__global__ __launch_bounds__(256) void transpose_split(
    const float* __restrict__ src0, const float* __restrict__ src1,
    unsigned short* __restrict__ hi, unsigned short* __restrict__ lo) {
  __shared__ float tile[32][33];
  int z = blockIdx.z;
  const float* src = (z < 8) ? src0 + (size_t)z * 524288 : src1 + (size_t)(z - 8) * 524288;
  int ci0 = blockIdx.y * 32, p0 = blockIdx.x * 32;
  int t = threadIdx.x;
  {
    int ci_l = t >> 5, p_l = t & 31;
#pragma unroll
    for (int j = 0; j < 4; j++)
      tile[ci_l + 8 * j][p_l] = src[(size_t)(ci0 + ci_l + 8 * j) * 1024 + p0 + p_l];
  }
  __syncthreads();
  {
    int p_l = t >> 3, cg = (t & 7) * 4;
    unsigned short hh[4], ll[4];
#pragma unroll
    for (int j = 0; j < 4; j++) {
      float v = tile[cg + j][p_l];
      hh[j] = bf16_rn(v);
      ll[j] = bf16_rn(v - __uint_as_float((unsigned)hh[j] << 16));
    }
    size_t idx = ((size_t)z * 1024 + p0 + p_l) * 512 + ci0 + cg;
    *(ushort4*)(hi + idx) = make_ushort4(hh[0], hh[1], hh[2], hh[3]);
    *(ushort4*)(lo + idx) = make_ushort4(ll[0], ll[1], ll[2], ll[3]);
  }
}

// Split-bf16 3-pass NT MFMA GEMM: D[m][n] = sum_k A[m][k]*B[n][k].
// Block 128x128, 4 waves 2x2, wave = 4x4 tiles of 16x16x32, K-step 64.
// AF32=1: A is fp32 (w1), split in-register during staging.
// KSPLIT=1: blockIdx.z = kh*8 + zb; K-range [kh*KTOT, (kh+1)*KTOT); EPI1 writes
//           partial S to S + kh*2097152, affine terms only when kh==0.
// EPI 0: +bias[m], emit bf16 hi/lo transposed [z][n][m] (conv1 -> Y1t)
// EPI 1: BN-folded scores epilogue -> S fp32 [z][m][n]
// EPI 2: fp32 store out[z][m][n] * p0[0]
template <int KTOT, int EPI, int AF32, int KSPLIT>
__global__ __launch_bounds__(256, 2) void gemm_nt(
    const void* __restrict__ Ahi_, const unsigned short* __restrict__ Alo,
    int aLD, long long aBS,
    const unsigned short* __restrict__ Bhi, const unsigned short* __restrict__ Blo,
    int bLD, long long bBS,
    void* __restrict__ out0, void* __restrict__ out1,
    const float* __restrict__ p0, const float* __restrict__ p1,
    const float* __restrict__ p2, const float* __restrict__ p3) {
  __shared__ __attribute__((aligned(16))) unsigned char smem[65536];
  int t = threadIdx.x;
  int z = blockIdx.z;
  int zb = z, kh = 0;
  if (KSPLIT) { zb = z & 7; kh = z >> 3; }
  int m0 = blockIdx.y * 128, n0 = blockIdx.x * 128;
  int w = t >> 6, lane = t & 63;
  int lm = lane & 15, q = lane >> 4;
  int mh = (w & 1) * 64, nh = (w >> 1) * 64;
  facc acc[4][4] = {};  // [mt][nt]
  for (int k0 = 0; k0 < KTOT; k0 += 64) {
    __syncthreads();
    if (AF32) {
      const float* Af = (const float*)Ahi_ + (size_t)zb * aBS;
#pragma unroll
      for (int j = 0; j < 8; j++) {
        int idx = t + 256 * j;
        int row = idx >> 4, c4 = idx & 15;
        float4 v = *(const float4*)(Af + (size_t)(m0 + row) * aLD + k0 + c4 * 4);
        unsigned short h0 = bf16_rn(v.x), h1 = bf16_rn(v.y), h2 = bf16_rn(v.z), h3 = bf16_rn(v.w);
        unsigned short l0 = bf16_rn(v.x - __uint_as_float((unsigned)h0 << 16));
        unsigned short l1 = bf16_rn(v.y - __uint_as_float((unsigned)h1 << 16));
        unsigned short l2 = bf16_rn(v.z - __uint_as_float((unsigned)h2 << 16));
        unsigned short l3 = bf16_rn(v.w - __uint_as_float((unsigned)h3 << 16));
        int base = row * 256 + (((c4 >> 1) ^ (row & 7)) * 16) + (c4 & 1) * 8;
        *(ushort4*)(smem + base) = make_ushort4(h0, h1, h2, h3);
        *(ushort4*)(smem + base + 128) = make_ushort4(l0, l1, l2, l3);
      }
    } else {
      const unsigned short* Ah = (const unsigned short*)Ahi_ + (size_t)zb * aBS + kh * KTOT;
      const unsigned short* Al = Alo + (size_t)zb * aBS + kh * KTOT;
#pragma unroll
      for (int j = 0; j < 8; j++) {
        int idx = t + 256 * j;
        int row = idx >> 4, c = idx & 15;
        const unsigned short* src = (c < 8) ? Ah : Al;
        uint4 v = *(const uint4*)(src + (size_t)(m0 + row) * aLD + k0 + (c & 7) * 8);
        *(uint4*)(smem + row * 256 + ((((c & 7) ^ (row & 7)) | (c & 8)) * 16)) = v;
      }
    }
#pragma unroll
    for (int j = 0; j < 8; j++) {
      int idx = t + 256 * j;
      int row = idx >> 4, c = idx & 15;
      const unsigned short* src = (c < 8) ? Bhi : Blo;
      uint4 v = *(const uint4*)(src + (size_t)zb * bBS + (size_t)kh * KTOT +
                                (size_t)(n0 + row) * bLD + k0 + (c & 7) * 8);
      *(uint4*)(smem + 32768 + row * 256 + ((((c & 7) ^ (row & 7)) | (c & 8)) * 16)) = v;
    }
    __syncthreads();
#pragma unroll
    for (int ks = 0; ks < 2; ks++) {
      bfrag ah[4], al[4], bh[4], bl[4];
#pragma unroll
      for (int mt = 0; mt < 4; mt++) {
        int m = mh + mt * 16 + lm;
        int phys = ((ks * 4 + q) ^ (m & 7)) * 16;
        const unsigned char* p = smem + m * 256;
        ah[mt] = *(const bfrag*)(p + phys);
        al[mt] = *(const bfrag*)(p + phys + 128);
      }
#pragma unroll
      for (int nt = 0; nt < 4; nt++) {
        int n = nh + nt * 16 + lm;
        int phys = ((ks * 4 + q) ^ (n & 7)) * 16;
        const unsigned char* p = smem + 32768 + n * 256;
        bh[nt] = *(const bfrag*)(p + phys);
        bl[nt] = *(const bfrag*)(p + phys + 128);
      }
#pragma unroll
      for (int mt = 0; mt < 4; mt++)
#pragma unroll
        for (int nt = 0; nt < 4; nt++) {
          acc[mt][nt] = __builtin_amdgcn_mfma_f32_16x16x32_bf16(ah[mt], bh[nt], acc[mt][nt], 0, 0, 0);
          acc[mt][nt] = __builtin_amdgcn_mfma_f32_16x16x32_bf16(ah[mt], bl[nt], acc[mt][nt], 0, 0, 0);
          acc[mt][nt] = __builtin_amdgcn_mfma_f32_16x16x32_bf16(al[mt], bh[nt], acc[mt][nt], 0, 0, 0);
        }
    }
  }
  if (EPI == 0) {
    unsigned short* Oh = (unsigned short*)out0;
    unsigned short* Ol = (unsigned short*)out1;
#pragma unroll
    for (int mt = 0; mt < 4; mt++) {
      int mb = m0 + mh + mt * 16 + q * 4;
#pragma unroll
      for (int nt = 0; nt < 4; nt++) {
        int n = n0 + nh + nt * 16 + lm;
        unsigned short hh[4], ll[4];
#pragma unroll
        for (int r = 0; r < 4; r++) {
          float v = acc[mt][nt][r] + p0[mb + r];
          hh[r] = bf16_rn(v);
          ll[r] = bf16_rn(v - __uint_as_float((unsigned)hh[r] << 16));
        }
        size_t o = ((size_t)(zb * 1024 + n)) * 256 + mb;
        *(ushort4*)(Oh + o) = make_ushort4(hh[0], hh[1], hh[2], hh[3]);
        *(ushort4*)(Ol + o) = make_ushort4(ll[0], ll[1], ll[2], ll[3]);
      }
    }
  } else if (EPI == 1) {
    // S = a1*a2*G (+ kh==0: a1*t2*r1 + t1*a2*r2 + 1024*t1*t2)
    float* S = (float*)out0 + (size_t)kh * 2097152;
    const float* stats = p0;
    const float* rowsum = p1;
    const float* gamma = p2;
    const float* bnb = p3;
    float a2v[4], t2v[4], r2v[4];
#pragma unroll
    for (int nt = 0; nt < 4; nt++) {
      int d = n0 + nh + nt * 16 + lm;
      float mu = stats[512 + d] * (1.f / 8192.f);
      float var = stats[1536 + d] * (1.f / 8192.f) - mu * mu;
      float a = gamma[d] * rsqrtf(var + 1e-5f);
      a2v[nt] = a;
      t2v[nt] = bnb[d] - mu * a;
      r2v[nt] = rowsum[(8 + zb) * 512 + d];
    }
#pragma unroll
    for (int mt = 0; mt < 4; mt++)
#pragma unroll
      for (int r = 0; r < 4; r++) {
        int c = m0 + mh + mt * 16 + q * 4 + r;
        float mu = stats[c] * (1.f / 8192.f);
        float var = stats[1024 + c] * (1.f / 8192.f) - mu * mu;
        float a1 = gamma[c] * rsqrtf(var + 1e-5f);
        float t1 = bnb[c] - mu * a1;
        float r1 = rowsum[zb * 512 + c];
#pragma unroll
        for (int nt = 0; nt < 4; nt++) {
          int d = n0 + nh + nt * 16 + lm;
          float sc = a1 * a2v[nt] * acc[mt][nt][r];
          if (kh == 0)
            sc += a1 * t2v[nt] * r1 + t1 * a2v[nt] * r2v[nt] + 1024.f * t1 * t2v[nt];
          S[((size_t)(zb * 512 + c)) * 512 + d] = sc;
        }
      }
  } else {
    float* O = (float*)out0;
    float sc = p0[0];
#pragma unroll
    for (int mt = 0; mt < 4; mt++)
#pragma unroll
      for (int r = 0; r < 4; r++) {
        int c = m0 + mh + mt * 16 + q * 4 + r;
#pragma unroll
        for (int nt = 0; nt < 4; nt++) {
          int n = n0 + nh + nt * 16 + lm;
          O[((size_t)(zb * 512 + c)) * 1024 + n] = sc * acc[mt][nt][r];
        }
      }
  }
}

// conv2 3x3 SAME 256->512, split-bf16 32x32x16 MFMA implicit GEMM.
// 512 threads (8 waves), 1 block/CU, grid (4 y, 4 co, 16 g) = 256 blocks.
// Block tile 128co x 256px (8 image rows). Wave tile 64co x 64px = 2x2 of 32x32.
// ci-chunk 16; all 9 taps staged per chunk; 32 barriers total.
// LDS: input halo 10 rows x 34 x [16ci hi+lo = 64B] = 21760 B at 0;
//      weights 9 taps x 128 co x 64B = 73728 B at 21760. Total 95488 B.
// Swizzle: entry e, 16B-chunk c (0,1=hi; 2,3=lo): off = e*64 + ((c^((e>>1)&3))<<4).
__global__ __launch_bounds__(512, 2) void conv3x3_mfma512(
    const unsigned short* __restrict__ Y1thi, const unsigned short* __restrict__ Y1tlo,
    const unsigned short* __restrict__ w2bhi, const unsigned short* __restrict__ w2blo,
    const float* __restrict__ b2, unsigned short* __restrict__ Fhi,
    unsigned short* __restrict__ Flo, float* __restrict__ stats,
    float* __restrict__ rowsum) {
  __shared__ __attribute__((aligned(16))) unsigned char smem[95488];
  const int WOFF = 21760;
  int t = threadIdx.x;
  int g = blockIdx.z;
  int co_base = blockIdx.y * 128;
  int y0 = blockIdx.x * 8;
  int w = t >> 6, l = t & 63;
  int l31 = l & 31, q2 = l >> 5;
  int co_half = (w & 1) * 64;
  int row_base = (w >> 1) * 2;
  facc16 acc[2][2] = {};
  for (int c16 = 0; c16 < 16; c16++) {
    int ci0 = c16 * 16;
    __syncthreads();
    for (int u = t; u < 1360; u += 512) {
      int e = u >> 2, c = u & 3;
      int srow = e / 34, sx = e - srow * 34;
      int gy = y0 - 1 + srow, gx = sx - 1;
      uint4 v = make_uint4(0u, 0u, 0u, 0u);
      if ((unsigned)gy < 32u && (unsigned)gx < 32u) {
        const unsigned short* src = (c < 2) ? Y1thi : Y1tlo;
        v = *(const uint4*)(src + (size_t)((g * 32 + gy) * 32 + gx) * 256 + ci0 + (c & 1) * 8);
      }
      *(uint4*)(smem + e * 64 + ((c ^ ((e >> 1) & 3)) << 4)) = v;
    }
    for (int u = t; u < 4608; u += 512) {
      int e = u >> 2, c = u & 3;
      int tap = e >> 7, co = e & 127;
      const unsigned short* src = (c < 2) ? w2bhi : w2blo;
      uint4 v = *(const uint4*)(src + (size_t)(tap * 512 + co_base + co) * 256 + ci0 + (c & 1) * 8);
      *(uint4*)(smem + WOFF + e * 64 + ((c ^ ((e >> 1) & 3)) << 4)) = v;
    }
    __syncthreads();
#pragma unroll
    for (int tap = 0; tap < 9; tap++) {
      const int dy = tap / 3, dx = tap % 3;
      bfrag ah[2], al[2], bh[2], bl[2];
#pragma unroll
      for (int jt = 0; jt < 2; jt++) {
        int cr = co_half + jt * 32 + l31;
        int ew = tap * 128 + cr;
        int off = WOFF + ew * 64 + ((q2 ^ ((ew >> 1) & 3)) << 4);
        ah[jt] = *(const bfrag*)(smem + off);
        al[jt] = *(const bfrag*)(smem + (off ^ 32));
      }
#pragma unroll
      for (int it = 0; it < 2; it++) {
        int ei = (row_base + it + dy) * 34 + l31 + dx;
        int off = ei * 64 + ((q2 ^ ((ei >> 1) & 3)) << 4);
        bh[it] = *(const bfrag*)(smem + off);
        bl[it] = *(const bfrag*)(smem + (off ^ 32));
      }
#pragma unroll
      for (int jt = 0; jt < 2; jt++)
#pragma unroll
        for (int it = 0; it < 2; it++) {
          acc[jt][it] = __builtin_amdgcn_mfma_f32_32x32x16_bf16(ah[jt], bh[it], acc[jt][it], 0, 0, 0);
          acc[jt][it] = __builtin_amdgcn_mfma_f32_32x32x16_bf16(ah[jt], bl[it], acc[jt][it], 0, 0, 0);
          acc[jt][it] = __builtin_amdgcn_mfma_f32_32x32x16_bf16(al[jt], bh[it], acc[jt][it], 0, 0, 0);
        }
    }
  }
  int grp = g >> 3;
  int pxg0 = blockIdx.x * 256 + (w >> 1) * 64;
#pragma unroll
  for (int jt = 0; jt < 2; jt++)
#pragma unroll
    for (int r = 0; r < 16; r++) {
      int co = co_base + co_half + jt * 32 + (r & 3) + 8 * (r >> 2) + 4 * q2;
      float bb = b2[co];
      float s = 0.f, s2 = 0.f;
#pragma unroll
      for (int it = 0; it < 2; it++) {
        float v = acc[jt][it][r] + bb;
        v = v > 0.f ? v : 0.01f * v;
        unsigned short h = bf16_rn(v);
        unsigned short lo_ = bf16_rn(v - __uint_as_float((unsigned)h << 16));
        size_t o = (size_t)(g * 512 + co) * 1024 + pxg0 + it * 32 + l31;
        Fhi[o] = h;
        Flo[o] = lo_;
        s += v;
        s2 = fmaf(v, v, s2);
      }
#pragma unroll
      for (int d = 1; d <= 16; d <<= 1) {
        s += __shfl_xor(s, d);
        s2 += __shfl_xor(s2, d);
      }
      if (l31 == 0) {
        atomicAdd(&stats[grp * 512 + co], s);
        atomicAdd(&stats[1024 + grp * 512 + co], s2);
        atomicAdd(&rowsum[g * 512 + co], s);
      }
    }
}

// Row softmax over 512; reads S0+S1 (K-split partials), writes att hi/lo in place
// into S0's row (hi ushorts [0:512), lo [512:1024)).
__global__ __launch_bounds__(256) void softmax_rows(float* __restrict__ S) {
  int row = blockIdx.x;
  float* p = S + (size_t)row * 512;
  const float* p1 = p + 2097152;
  int t = threadIdx.x;
  float2 va = *(const float2*)(p + 2 * t);
  float2 vb = *(const float2*)(p1 + 2 * t);
  float vx = va.x + vb.x, vy = va.y + vb.y;
  float mx = fmaxf(vx, vy);
#pragma unroll
  for (int d = 32; d >= 1; d >>= 1) mx = fmaxf(mx, __shfl_xor(mx, d));
  __shared__ float sred[8];
  int wave = t >> 6, lane = t & 63;
  if (lane == 0) sred[wave] = mx;
  __syncthreads();
  float m4 = fmaxf(fmaxf(sred[0], sred[1]), fmaxf(sred[2], sred[3]));
  float ex = expf(vx - m4), ey = expf(vy - m4);
  float s = ex + ey;
#pragma unroll
  for (int d = 32; d >= 1; d >>= 1) s += __shfl_xor(s, d);
  if (lane == 0) sred[4 + wave] = s;
  __syncthreads();
  float inv = 1.f / (sred[4] + sred[5] + sred[6] + sred[7]);
  float px_ = ex * inv, py_ = ey * inv;
  unsigned short h0 = bf16_rn(px_), h1 = bf16_rn(py_);
  unsigned short l0 = bf16_rn(px_ - __uint_as_float((unsigned)h0 << 16));
  unsigned short l1 = bf16_rn(py_ - __uint_as_float((unsigned)h1 << 16));
  unsigned short* rh = (unsigned short*)p;
  *(ushort2*)(rh + 2 * t) = make_ushort2(h0, h1);
  *(ushort2*)(rh + 512 + 2 * t) = make_ushort2(l0, l1);
}

extern "C" void kernel_launch(void* const* d_in, const int* in_sizes, int n_in,
                              void* d_out, int out_size, void* d_ws, size_t ws_size,
                              hipStream_t stream) {
  const float* x = (const float*)d_in[0];
  const float* x1 = (const float*)d_in[1];
  const float* x2 = (const float*)d_in[2];
  const float* w1 = (const float*)d_in[3];
  const float* b1 = (const float*)d_in[4];
  const float* w2 = (const float*)d_in[5];
  const float* b2 = (const float*)d_in[6];
  const float* gamma = (const float*)d_in[7];
  const float* bnb = (const float*)d_in[8];
  const float* beta = (const float*)d_in[9];
  float* out = (float*)d_out;
  float* ws = (float*)d_ws;

  // Region RF [0 : 8388608): x12t -> F(yhat) -> xt
  unsigned short* x12thi = (unsigned short*)ws;             // 16x1024x512
  unsigned short* x12tlo = (unsigned short*)(ws + 4194304);
  unsigned short* Fhi = (unsigned short*)ws;                // 16x512x1024
  unsigned short* Flo = (unsigned short*)(ws + 4194304);
  unsigned short* xthi = (unsigned short*)ws;               // 8x1024x512
  unsigned short* xtlo = (unsigned short*)(ws + 2097152);
  // Region RY [8388608 : 12582912): Y1t -> S0/S1 (att in S0)
  unsigned short* Y1thi = (unsigned short*)(ws + 8388608);  // 16x1024x256
  unsigned short* Y1tlo = (unsigned short*)(ws + 10485760);
  float* S = ws + 8388608;                                  // S0; S1 at +2097152
  // Persistent
  unsigned short* w2bhi = (unsigned short*)(ws + 12582912);
  unsigned short* w2blo = (unsigned short*)(ws + 13172736);
  float* stats = ws + 13762560;   // 2048 (+ rowsum 8192 contiguous)
  float* rowsum = ws + 13764608;

  // w2 prep + zero stats/rowsum
  prep_w2<<<512, 256, 0, stream>>>(w2, w2bhi, w2blo, stats);
  // x1,x2 -> x12t [g][px][ci] hi/lo
  transpose_split<<<dim3(32, 16, 16), 256, 0, stream>>>(x1, x2, x12thi, x12tlo);
  // conv1: D[co][px] = sum_ci w1*x, +b1, emit Y1t [g][px][co] hi/lo
  gemm_nt<512, 0, 1, 0><<<dim3(8, 2, 16), 256, 0, stream>>>(
      w1, nullptr, 512, 0LL, x12thi, x12tlo, 512, 524288LL,
      Y1thi, Y1tlo, b1, nullptr, nullptr, nullptr);
  // conv2 + bias + LeakyReLU -> yhat split + stats + rowsums
  conv3x3_mfma512<<<dim3(4, 4, 16), 512, 0, stream>>>(
      Y1thi, Y1tlo, w2bhi, w2blo, b2, Fhi, Flo, stats, rowsum);
  // scores (K-split x2) with BN folded -> S0, S1
  gemm_nt<512, 1, 0, 1><<<dim3(4, 4, 16), 256, 0, stream>>>(
      Fhi, Flo, 1024, 524288LL, Fhi + (size_t)8 * 524288, Flo + (size_t)8 * 524288,
      1024, 524288LL, S, nullptr, stats, rowsum, gamma, bnb);
  // x -> xt [b][px][c] hi/lo (F dead; overwrites RF front)
  transpose_split<<<dim3(32, 16, 8), 256, 0, stream>>>(x, x, xthi, xtlo);
  // softmax (S0+S1) in place -> att hi/lo packed in S0 rows
  softmax_rows<<<4096, 256, 0, stream>>>(S);
  // out: O[c][px] = beta * sum_d att*xt
  gemm_nt<512, 2, 0, 0><<<dim3(8, 4, 8), 256, 0, stream>>>(
      (unsigned short*)S, (unsigned short*)S + 512, 1024, 524288LL,
      xthi, xtlo, 512, 524288LL, out, nullptr, beta, nullptr, nullptr, nullptr);
}